// Round 5
// baseline (896.745 us; speedup 1.0000x reference)
//
#include <hip/hip_runtime.h>
#include <cstdint>
#include <cstddef>

typedef __bf16 bf16x8 __attribute__((ext_vector_type(8)));
typedef float f32x4 __attribute__((ext_vector_type(4)));
typedef unsigned short us16;

__device__ __forceinline__ float lrelu(float v) { return v >= 0.0f ? v : 0.01f * v; }
__device__ __forceinline__ float fsigmoid(float x) {
  x = fminf(fmaxf(x, -30.0f), 30.0f);
  return 1.0f / (1.0f + __expf(-x));
}
__device__ __forceinline__ float ftanh(float x) {
  x = fminf(fmaxf(x, -15.0f), 15.0f);
  float e = __expf(2.0f * x);
  return (e - 1.0f) / (e + 1.0f);
}
__device__ __forceinline__ us16 f2b(float f) {
  unsigned int u = __builtin_bit_cast(unsigned int, f);
  u = (u + 0x7fffu + ((u >> 16) & 1u)) >> 16;
  return (us16)u;
}
__device__ __forceinline__ float b2f(us16 h) {
  unsigned int u = ((unsigned int)h) << 16;
  return __builtin_bit_cast(float, u);
}
__device__ __forceinline__ unsigned pk2(float a, float b) {
  return (unsigned)f2b(a) | ((unsigned)f2b(b) << 16);
}
__device__ __forceinline__ void unp8(int4 v, float* t) {
  unsigned a = (unsigned)v.x, b = (unsigned)v.y, c = (unsigned)v.z, d = (unsigned)v.w;
  t[0] = b2f((us16)(a & 0xffff)); t[1] = b2f((us16)(a >> 16));
  t[2] = b2f((us16)(b & 0xffff)); t[3] = b2f((us16)(b >> 16));
  t[4] = b2f((us16)(c & 0xffff)); t[5] = b2f((us16)(c >> 16));
  t[6] = b2f((us16)(d & 0xffff)); t[7] = b2f((us16)(d >> 16));
}

// async global->LDS, 16B per lane; ldst is the wave-uniform base, HW adds lane*16
__device__ __forceinline__ void stage16(const us16* gsrc, us16* ldst) {
  __builtin_amdgcn_global_load_lds(
      (const __attribute__((address_space(1))) unsigned int*)(const void*)gsrc,
      (__attribute__((address_space(3))) unsigned int*)(void*)ldst, 16, 0, 0);
}
// swizzled frag read: tile rows are 64 bf16 (128B); slot c holds global chunk c^(row&7)
__device__ __forceinline__ bf16x8 frag_rd(const us16* base, int row, int byte_in_row) {
  int byte = row * 128 + (byte_in_row ^ ((row & 7) << 4));
  return *(const bf16x8*)((const char*)base + byte);
}

// ---------------- degree / norm / CSR build ----------------
__global__ void k_deg(const int* __restrict__ dst, int* __restrict__ indeg, int E) {
  int e = blockIdx.x * 256 + threadIdx.x;
  if (e < E) atomicAdd(&indeg[dst[e]], 1);
}

__global__ void k_dis(const int* __restrict__ indeg, float* __restrict__ dis, int n) {
  int i = blockIdx.x * 256 + threadIdx.x;
  if (i < n) dis[i] = rsqrtf((float)(indeg[i] + 1));  // +1 self-loop
}

// 3-phase parallel exclusive scan of indeg -> rp
__global__ __launch_bounds__(1024) void k_scan1(const int* __restrict__ v, int* __restrict__ rp,
                                                int* __restrict__ part, int n) {
  __shared__ int wsum[16];
  int base = blockIdx.x << 10;
  int t = threadIdx.x, lane = t & 63, wv = t >> 6;
  int val = (base + t < n) ? v[base + t] : 0;
  int s = val;
  #pragma unroll
  for (int off = 1; off < 64; off <<= 1) {
    int u = __shfl_up(s, off);
    if (lane >= off) s += u;
  }
  if (lane == 63) wsum[wv] = s;
  __syncthreads();
  int wadd = 0;
  #pragma unroll
  for (int w = 0; w < 16; ++w) wadd += (w < wv) ? wsum[w] : 0;
  if (base + t < n) rp[base + t] = wadd + s - val;
  if (t == 0) {
    int tot = 0;
    #pragma unroll
    for (int w = 0; w < 16; ++w) tot += wsum[w];
    part[blockIdx.x] = tot;
  }
}

__global__ __launch_bounds__(1024) void k_scan2(int* __restrict__ p, int nc) {
  __shared__ int wsum[16];
  int t = threadIdx.x, lane = t & 63, wv = t >> 6;
  int val = (t < nc) ? p[t] : 0;
  int s = val;
  #pragma unroll
  for (int off = 1; off < 64; off <<= 1) {
    int u = __shfl_up(s, off);
    if (lane >= off) s += u;
  }
  if (lane == 63) wsum[wv] = s;
  __syncthreads();
  int wadd = 0;
  #pragma unroll
  for (int w = 0; w < 16; ++w) wadd += (w < wv) ? wsum[w] : 0;
  if (t < nc) p[t] = wadd + s - val;
}

__global__ void k_scan3(int* __restrict__ rp, const int* __restrict__ part, int n, int total) {
  int i = blockIdx.x * 256 + threadIdx.x;
  if (i < n) rp[i] += part[i >> 10];
  else if (i == n) rp[n] = total;
}

__global__ void k_fill(const int* __restrict__ src, const int* __restrict__ dst,
                       const float* __restrict__ dis, int* __restrict__ cursor,
                       int* __restrict__ csrc, float* __restrict__ cw, int E) {
  int e = blockIdx.x * 256 + threadIdx.x;
  if (e >= E) return;
  int s = src[e], d = dst[e];
  int pos = atomicAdd(&cursor[d], 1);
  csrc[pos] = s;
  cw[pos] = dis[s] * dis[d];
}

// ---------------- repack: fp32 -> bf16 cast / transpose ----------------
__global__ void k_cast(const float* __restrict__ in, us16* __restrict__ out, int n) {
  int i = (blockIdx.x * 256 + threadIdx.x) * 4;
  if (i >= n) return;
  float4 v = *(const float4*)(in + i);
  *(ushort4*)(out + i) = make_ushort4(f2b(v.x), f2b(v.y), f2b(v.z), f2b(v.w));
}

// in [R,C] fp32 -> out [C,R] bf16
__global__ void k_tpose(const float* __restrict__ in, us16* __restrict__ out, int R, int C) {
  int t = blockIdx.x * 256 + threadIdx.x;
  if (t >= R * C) return;
  int r = t % R, c = t / R;
  out[(size_t)c * R + r] = f2b(in[(size_t)r * C + c]);
}

// ---------------- bf16 MFMA GEMM: C = act(A[M,K] @ Bt[Nc,K]^T + bias) ----------------
// block 128x128, 4 waves (2x2), wave tile 64x64, K-step 64.
// global_load_lds staging, linear LDS + source-swizzled chunks, swizzled frag reads.
template<int ACT, int BIAS>
__global__ __launch_bounds__(256) void k_mm(const us16* __restrict__ A,
                                            const us16* __restrict__ Bt,
                                            const float* __restrict__ bias,
                                            us16* __restrict__ Cb,
                                            int M, int K, int Nc, int ny) {
  __shared__ __align__(16) us16 As[128 * 64];
  __shared__ __align__(16) us16 Bs[128 * 64];
  const int bm = (blockIdx.x / ny) * 128;
  const int bn = (blockIdx.x % ny) * 128;
  const int tid = threadIdx.x;
  const int lane = tid & 63;
  const int wave = tid >> 6;
  const int wm = (wave >> 1) * 64;
  const int wn = (wave & 1) * 64;
  const int lr = lane & 15;
  const int lk = lane >> 4;
  const int srow = lane >> 3;                 // 0..7 within one staging instr
  const int schk = (lane & 7) ^ srow;         // swizzled source chunk (8 bf16)
  f32x4 acc[4][4] = {};
  for (int k0 = 0; k0 < K; k0 += 64) {
    #pragma unroll
    for (int it = 0; it < 4; ++it) {
      int r8 = (wave * 4 + it) * 8;
      int ar = bm + r8 + srow; if (ar >= M) ar = M - 1;
      stage16(A + (size_t)ar * K + k0 + schk * 8, As + r8 * 64);
      stage16(Bt + (size_t)(bn + r8 + srow) * K + k0 + schk * 8, Bs + r8 * 64);
    }
    __syncthreads();
    #pragma unroll
    for (int kk = 0; kk < 2; ++kk) {
      bf16x8 af[4], bq[4];
      #pragma unroll
      for (int i = 0; i < 4; ++i) af[i] = frag_rd(As, wm + i * 16 + lr, kk * 64 + lk * 16);
      #pragma unroll
      for (int j = 0; j < 4; ++j) bq[j] = frag_rd(Bs, wn + j * 16 + lr, kk * 64 + lk * 16);
      #pragma unroll
      for (int i = 0; i < 4; ++i)
        #pragma unroll
        for (int j = 0; j < 4; ++j)
          acc[i][j] = __builtin_amdgcn_mfma_f32_16x16x32_bf16(af[i], bq[j], acc[i][j], 0, 0, 0);
    }
    __syncthreads();
  }
  float bb[4];
  #pragma unroll
  for (int j = 0; j < 4; ++j) bb[j] = BIAS ? bias[bn + wn + j * 16 + lr] : 0.0f;
  #pragma unroll
  for (int i = 0; i < 4; ++i) {
    #pragma unroll
    for (int q = 0; q < 4; ++q) {
      int row = bm + wm + i * 16 + lk * 4 + q;
      if (row < M) {
        #pragma unroll
        for (int j = 0; j < 4; ++j) {
          int col = bn + wn + j * 16 + lr;
          float v = acc[i][j][q] + bb[j];
          if (ACT) v = lrelu(v);
          Cb[(size_t)row * Nc + col] = f2b(v);
        }
      }
    }
  }
}

// ---------------- CSR aggregation, F=128, edge loop unrolled x4 ----------------
template<int ACT>
__global__ __launch_bounds__(256) void k_agg128(const us16* __restrict__ hw, const int* __restrict__ rp,
                                                const int* __restrict__ csrc, const float* __restrict__ cw,
                                                const float* __restrict__ dis, const float* __restrict__ bias,
                                                us16* __restrict__ outp, int M) {
  int node = blockIdx.x * 16 + (threadIdx.x >> 4);
  int l = threadIdx.x & 15;
  if (node >= M) return;
  const us16* base = hw + l * 8;
  float acc[8], t0[8], t1[8], t2[8], t3[8];
  float dn = dis[node];
  float sw = dn * dn;
  {
    int4 v = *(const int4*)(base + (size_t)node * 128);
    unp8(v, t0);
    #pragma unroll
    for (int j = 0; j < 8; ++j) acc[j] = t0[j] * sw;
  }
  int e = rp[node], e1 = rp[node + 1];
  for (; e + 4 <= e1; e += 4) {
    int s0 = csrc[e], s1 = csrc[e + 1], s2 = csrc[e + 2], s3 = csrc[e + 3];
    float w0 = cw[e], w1 = cw[e + 1], w2 = cw[e + 2], w3 = cw[e + 3];
    int4 v0 = *(const int4*)(base + (size_t)s0 * 128);
    int4 v1 = *(const int4*)(base + (size_t)s1 * 128);
    int4 v2 = *(const int4*)(base + (size_t)s2 * 128);
    int4 v3 = *(const int4*)(base + (size_t)s3 * 128);
    unp8(v0, t0); unp8(v1, t1); unp8(v2, t2); unp8(v3, t3);
    #pragma unroll
    for (int j = 0; j < 8; ++j) acc[j] = fmaf(w0, t0[j], acc[j]);
    #pragma unroll
    for (int j = 0; j < 8; ++j) acc[j] = fmaf(w1, t1[j], acc[j]);
    #pragma unroll
    for (int j = 0; j < 8; ++j) acc[j] = fmaf(w2, t2[j], acc[j]);
    #pragma unroll
    for (int j = 0; j < 8; ++j) acc[j] = fmaf(w3, t3[j], acc[j]);
  }
  for (; e < e1; ++e) {
    int s0 = csrc[e];
    float w0 = cw[e];
    int4 v0 = *(const int4*)(base + (size_t)s0 * 128);
    unp8(v0, t0);
    #pragma unroll
    for (int j = 0; j < 8; ++j) acc[j] = fmaf(w0, t0[j], acc[j]);
  }
  if (ACT) {
    float4 b0 = *(const float4*)(bias + l * 8);
    float4 b1 = *(const float4*)(bias + l * 8 + 4);
    float bb[8] = {b0.x, b0.y, b0.z, b0.w, b1.x, b1.y, b1.z, b1.w};
    #pragma unroll
    for (int j = 0; j < 8; ++j) acc[j] = lrelu(acc[j] + bb[j]);
  }
  int4 o;
  o.x = (int)pk2(acc[0], acc[1]);
  o.y = (int)pk2(acc[2], acc[3]);
  o.z = (int)pk2(acc[4], acc[5]);
  o.w = (int)pk2(acc[6], acc[7]);
  *(int4*)(outp + (size_t)node * 128 + l * 8) = o;
}

// ---------------- fused GRU cell, two-pass (MFMA): emb = GRUCell(x, hprev) ----------------
// Block 128 rows x 64 H-cols, 4 waves (2 wm x 2 wn), wave tile 64x32, K-step 64.
// Pass 1: gi = x@Wih^T (3 gates) -> packed bf16 in regs. Pass 2: gh = h@Whh^T (3 gates).
// Epilogue combines gates; z*h reads bf16 h from global (L2-warm).
template<int H, int WB>
__global__ __launch_bounds__(256) void k_fgru(const us16* __restrict__ xb, const us16* __restrict__ hb,
                                              const us16* __restrict__ Wih, const us16* __restrict__ Whh,
                                              const float* __restrict__ bih, const float* __restrict__ bhh,
                                              float* __restrict__ emb, us16* __restrict__ embb,
                                              int M, int ny) {
  __shared__ __align__(16) us16 as_[128 * 64];    // x or h tile
  __shared__ __align__(16) us16 ws[3 * 64 * 64];  // 3 gates x 64 cols x 64 k
  const int bn = (blockIdx.x % ny) * 64;
  const int bm = (blockIdx.x / ny) * 128;
  const int tid = threadIdx.x;
  const int lane = tid & 63, wave = tid >> 6;
  const int wm = (wave >> 1) * 64, wn = (wave & 1) * 32;
  const int lr = lane & 15, lk = lane >> 4;
  const int srow = lane >> 3;
  const int schk = (lane & 7) ^ srow;

  f32x4 acc[3][4][2];
  #pragma unroll
  for (int g = 0; g < 3; ++g)
    #pragma unroll
    for (int i = 0; i < 4; ++i)
      #pragma unroll
      for (int j = 0; j < 2; ++j) acc[g][i][j] = {0.f, 0.f, 0.f, 0.f};

  // ---- pass 1: gi (A = x, W = Wih) ----
  for (int k0 = 0; k0 < H; k0 += 64) {
    #pragma unroll
    for (int it = 0; it < 4; ++it) {
      int r8 = (wave * 4 + it) * 8;
      int ar = bm + r8 + srow; if (ar >= M) ar = M - 1;
      stage16(xb + (size_t)ar * H + k0 + schk * 8, as_ + r8 * 64);
    }
    #pragma unroll
    for (int it = 0; it < 6; ++it) {
      int idx = wave * 6 + it;
      int g = idx >> 3, rr = (idx & 7) * 8;
      stage16(Wih + (size_t)(g * H + bn + rr + srow) * H + k0 + schk * 8,
              ws + g * 64 * 64 + rr * 64);
    }
    __syncthreads();
    #pragma unroll
    for (int kk = 0; kk < 2; ++kk) {
      bf16x8 a[4], bq[3][2];
      #pragma unroll
      for (int i = 0; i < 4; ++i) a[i] = frag_rd(as_, wm + i * 16 + lr, kk * 64 + lk * 16);
      #pragma unroll
      for (int g = 0; g < 3; ++g)
        #pragma unroll
        for (int j = 0; j < 2; ++j)
          bq[g][j] = frag_rd(ws + g * 64 * 64, wn + j * 16 + lr, kk * 64 + lk * 16);
      #pragma unroll
      for (int g = 0; g < 3; ++g)
        #pragma unroll
        for (int i = 0; i < 4; ++i)
          #pragma unroll
          for (int j = 0; j < 2; ++j)
            acc[g][i][j] = __builtin_amdgcn_mfma_f32_16x16x32_bf16(a[i], bq[g][j], acc[g][i][j], 0, 0, 0);
    }
    __syncthreads();
  }
  // pack gi to bf16 pairs (48 regs), reset acc for pass 2
  uint2 pgi[3][4][2];
  #pragma unroll
  for (int g = 0; g < 3; ++g)
    #pragma unroll
    for (int i = 0; i < 4; ++i)
      #pragma unroll
      for (int j = 0; j < 2; ++j) {
        pgi[g][i][j].x = pk2(acc[g][i][j][0], acc[g][i][j][1]);
        pgi[g][i][j].y = pk2(acc[g][i][j][2], acc[g][i][j][3]);
        acc[g][i][j] = {0.f, 0.f, 0.f, 0.f};
      }
  // ---- pass 2: gh (A = h, W = Whh) ----
  for (int k0 = 0; k0 < H; k0 += 64) {
    #pragma unroll
    for (int it = 0; it < 4; ++it) {
      int r8 = (wave * 4 + it) * 8;
      int ar = bm + r8 + srow; if (ar >= M) ar = M - 1;
      stage16(hb + (size_t)ar * H + k0 + schk * 8, as_ + r8 * 64);
    }
    #pragma unroll
    for (int it = 0; it < 6; ++it) {
      int idx = wave * 6 + it;
      int g = idx >> 3, rr = (idx & 7) * 8;
      stage16(Whh + (size_t)(g * H + bn + rr + srow) * H + k0 + schk * 8,
              ws + g * 64 * 64 + rr * 64);
    }
    __syncthreads();
    #pragma unroll
    for (int kk = 0; kk < 2; ++kk) {
      bf16x8 a[4], bq[3][2];
      #pragma unroll
      for (int i = 0; i < 4; ++i) a[i] = frag_rd(as_, wm + i * 16 + lr, kk * 64 + lk * 16);
      #pragma unroll
      for (int g = 0; g < 3; ++g)
        #pragma unroll
        for (int j = 0; j < 2; ++j)
          bq[g][j] = frag_rd(ws + g * 64 * 64, wn + j * 16 + lr, kk * 64 + lk * 16);
      #pragma unroll
      for (int g = 0; g < 3; ++g)
        #pragma unroll
        for (int i = 0; i < 4; ++i)
          #pragma unroll
          for (int j = 0; j < 2; ++j)
            acc[g][i][j] = __builtin_amdgcn_mfma_f32_16x16x32_bf16(a[i], bq[g][j], acc[g][i][j], 0, 0, 0);
    }
    __syncthreads();
  }
  // ---- epilogue: gates ----
  #pragma unroll
  for (int j = 0; j < 2; ++j) {
    int col = bn + wn + j * 16 + lr;
    float sr = bih[col] + bhh[col];
    float sz = bih[H + col] + bhh[H + col];
    float bni = bih[2 * H + col];
    float bnh = bhh[2 * H + col];
    #pragma unroll
    for (int i = 0; i < 4; ++i) {
      #pragma unroll
      for (int q = 0; q < 4; ++q) {
        int row = bm + wm + i * 16 + lk * 4 + q;
        if (row >= M) continue;
        unsigned w0 = (q & 2) ? pgi[0][i][j].y : pgi[0][i][j].x;
        unsigned w1 = (q & 2) ? pgi[1][i][j].y : pgi[1][i][j].x;
        unsigned w2 = (q & 2) ? pgi[2][i][j].y : pgi[2][i][j].x;
        int sh = (q & 1) * 16;
        float gir = b2f((us16)(w0 >> sh));
        float giz = b2f((us16)(w1 >> sh));
        float gin = b2f((us16)(w2 >> sh));
        float r = fsigmoid(gir + acc[0][i][j][q] + sr);
        float z = fsigmoid(giz + acc[1][i][j][q] + sz);
        float n = ftanh(gin + bni + r * (acc[2][i][j][q] + bnh));
        float hv = b2f(hb[(size_t)row * H + col]);
        float o = (1.0f - z) * n + z * hv;
        emb[(size_t)row * H + col] = o;
        if (WB) embb[(size_t)row * H + col] = f2b(o);
      }
    }
  }
}

// ---------------- post head: out[n] = sum_cols(emb1 @ Wpost + bpost) ----------------
__global__ __launch_bounds__(256) void k_post(const float* __restrict__ emb, const float* __restrict__ Wpost,
                                              const float* __restrict__ bpost, float* __restrict__ outv, int M) {
  int gw = (int)((blockIdx.x * 256 + threadIdx.x) >> 6);
  int lane = threadIdx.x & 63;
  if (gw >= M) return;
  float2 ev = *(const float2*)(emb + (size_t)gw * 128 + lane * 2);
  float4 wv = *(const float4*)(Wpost + lane * 4);
  float p = ev.x * (wv.x + wv.y) + ev.y * (wv.z + wv.w);
  #pragma unroll
  for (int o = 32; o > 0; o >>= 1) p += __shfl_xor(p, o);
  if (lane == 0) outv[gw] = p + bpost[0] + bpost[1];
}

extern "C" void kernel_launch(void* const* d_in, const int* in_sizes, int n_in,
                              void* d_out, int out_size, void* d_ws, size_t ws_size,
                              hipStream_t stream) {
  const float* x     = (const float*)d_in[0];
  const int*   ei    = (const int*)d_in[1];
  const float* prev0 = (const float*)d_in[2];
  const float* prev1 = (const float*)d_in[3];
  const float* Wp1   = (const float*)d_in[4];
  const float* bp1   = (const float*)d_in[5];
  const float* Wp2   = (const float*)d_in[6];
  const float* bp2   = (const float*)d_in[7];
  const float* Wc1   = (const float*)d_in[8];
  const float* bc1   = (const float*)d_in[9];
  const float* Wc2   = (const float*)d_in[10];
  const float* bc2   = (const float*)d_in[11];
  const float* Wih1  = (const float*)d_in[12];
  const float* Whh1  = (const float*)d_in[13];
  const float* bih1  = (const float*)d_in[14];
  const float* bhh1  = (const float*)d_in[15];
  const float* Wih2  = (const float*)d_in[16];
  const float* Whh2  = (const float*)d_in[17];
  const float* bih2  = (const float*)d_in[18];
  const float* bhh2  = (const float*)d_in[19];
  const float* Wpost = (const float*)d_in[20];
  const float* bpost = (const float*)d_in[21];

  const int N = in_sizes[0] / 128;   // 100000
  const int E = in_sizes[1] / 2;     // 1600000
  const int* srcp = ei;
  const int* dstp = ei + E;

  char* wsb = (char*)d_ws;
  size_t off = 0;
  auto alloc = [&](size_t bytes) -> void* {
    void* p = wsb + off;
    off = (off + bytes + 255) & ~(size_t)255;
    return p;
  };
  float* dis    = (float*)alloc((size_t)N * 4);
  int*   indeg  = (int*)alloc((size_t)N * 4);
  int*   rp     = (int*)alloc((size_t)(N + 1) * 4);
  int*   part   = (int*)alloc((size_t)1024 * 4);
  int*   cursor = (int*)alloc((size_t)N * 4);
  int*   csrc   = (int*)alloc((size_t)E * 4);
  float* cw     = (float*)alloc((size_t)E * 4);
  us16* xb    = (us16*)alloc((size_t)N * 128 * 2);
  us16* p0b   = (us16*)alloc((size_t)N * 256 * 2);
  us16* p1b   = (us16*)alloc((size_t)N * 128 * 2);
  us16* WtP1  = (us16*)alloc((size_t)256 * 128 * 2);
  us16* WtP2  = (us16*)alloc((size_t)128 * 256 * 2);
  us16* WtC1  = (us16*)alloc((size_t)256 * 128 * 2);
  us16* WtC2  = (us16*)alloc((size_t)128 * 256 * 2);
  us16* Wih1b = (us16*)alloc((size_t)768 * 256 * 2);
  us16* Whh1b = (us16*)alloc((size_t)768 * 256 * 2);
  us16* Wih2b = (us16*)alloc((size_t)384 * 128 * 2);
  us16* Whh2b = (us16*)alloc((size_t)384 * 128 * 2);
  us16* bufA  = (us16*)alloc((size_t)N * 256 * 2);  // MLP hidden / GCN1 out
  us16* bufB  = (us16*)alloc((size_t)N * 128 * 2);  // MLP out / GCN2 lin out
  us16* bufD  = (us16*)alloc((size_t)N * 128 * 2);  // agg out
  us16* emb0b = (us16*)alloc((size_t)N * 256 * 2);
  (void)ws_size; (void)n_in; (void)out_size;

  float* outv = (float*)d_out;
  float* emb0 = outv + N;
  float* emb1 = emb0 + (size_t)N * 256;

  auto cg = [](long n) { return (unsigned)((n / 4 + 255) / 256); };

  // weight/activation repack
  k_cast<<<cg((long)N * 128), 256, 0, stream>>>(x, xb, N * 128);
  k_cast<<<cg((long)N * 256), 256, 0, stream>>>(prev0, p0b, N * 256);
  k_cast<<<cg((long)N * 128), 256, 0, stream>>>(prev1, p1b, N * 128);
  k_cast<<<cg(768 * 256), 256, 0, stream>>>(Wih1, Wih1b, 768 * 256);
  k_cast<<<cg(768 * 256), 256, 0, stream>>>(Whh1, Whh1b, 768 * 256);
  k_cast<<<cg(384 * 128), 256, 0, stream>>>(Wih2, Wih2b, 384 * 128);
  k_cast<<<cg(384 * 128), 256, 0, stream>>>(Whh2, Whh2b, 384 * 128);
  k_tpose<<<(128 * 256 + 255) / 256, 256, 0, stream>>>(Wp1, WtP1, 128, 256);
  k_tpose<<<(256 * 128 + 255) / 256, 256, 0, stream>>>(Wp2, WtP2, 256, 128);
  k_tpose<<<(128 * 256 + 255) / 256, 256, 0, stream>>>(Wc1, WtC1, 128, 256);
  k_tpose<<<(256 * 128 + 255) / 256, 256, 0, stream>>>(Wc2, WtC2, 256, 128);

  // CSR build (parallel scan)
  hipMemsetAsync(indeg, 0, (size_t)N * 4, stream);
  k_deg<<<(E + 255) / 256, 256, 0, stream>>>(dstp, indeg, E);
  k_dis<<<(N + 255) / 256, 256, 0, stream>>>(indeg, dis, N);
  const int NC = (N + 1023) / 1024;  // 98
  k_scan1<<<NC, 1024, 0, stream>>>(indeg, rp, part, N);
  k_scan2<<<1, 1024, 0, stream>>>(part, NC);
  k_scan3<<<(N + 256) / 256, 256, 0, stream>>>(rp, part, N, E);
  hipMemcpyAsync(cursor, rp, (size_t)N * 4, hipMemcpyDeviceToDevice, stream);
  k_fill<<<(E + 255) / 256, 256, 0, stream>>>(srcp, dstp, dis, cursor, csrc, cw, E);

  const int MB = (N + 127) / 128;   // 782 (k_mm, k_fgru)
  const int AB = (N + 15) / 16;     // 6250 (k_agg128)

  // preprocess MLP
  k_mm<1, 1><<<MB * 2, 256, 0, stream>>>(xb, WtP1, bp1, bufA, N, 128, 256, 2);
  k_mm<1, 1><<<MB, 256, 0, stream>>>(bufA, WtP2, bp2, bufB, N, 256, 128, 1);
  // GCN1: aggregate FIRST (linearity), then linear+bias+leaky
  k_agg128<0><<<AB, 256, 0, stream>>>(bufB, rp, csrc, cw, dis, nullptr, bufD, N);
  k_mm<1, 1><<<MB * 2, 256, 0, stream>>>(bufD, WtC1, bc1, bufA, N, 128, 256, 2);
  // GRU1 fused (two-pass), bn-inner for L2 reuse
  k_fgru<256, 1><<<MB * 4, 256, 0, stream>>>(bufA, p0b, Wih1b, Whh1b, bih1, bhh1,
                                             emb0, emb0b, N, 4);
  // GCN2: linear first (256->128), then aggregate with bias+leaky
  k_mm<0, 0><<<MB, 256, 0, stream>>>(emb0b, WtC2, nullptr, bufB, N, 256, 128, 1);
  k_agg128<1><<<AB, 256, 0, stream>>>(bufB, rp, csrc, cw, dis, bc2, bufD, N);
  // GRU2 fused
  k_fgru<128, 0><<<MB * 2, 256, 0, stream>>>(bufD, p1b, Wih2b, Whh2b, bih2, bhh2,
                                             emb1, nullptr, N, 2);
  // post head
  k_post<<<(N + 3) / 4, 256, 0, stream>>>(emb1, Wpost, bpost, outv, N);
}

// Round 6
// 799.917 us; speedup vs baseline: 1.1210x; 1.1210x over previous
//
#include <hip/hip_runtime.h>
#include <cstdint>
#include <cstddef>

typedef __bf16 bf16x8 __attribute__((ext_vector_type(8)));
typedef float f32x4 __attribute__((ext_vector_type(4)));
typedef unsigned short us16;

__device__ __forceinline__ float lrelu(float v) { return v >= 0.0f ? v : 0.01f * v; }
__device__ __forceinline__ float fsigmoid(float x) {
  x = fminf(fmaxf(x, -30.0f), 30.0f);
  return 1.0f / (1.0f + __expf(-x));
}
__device__ __forceinline__ float ftanh(float x) {
  x = fminf(fmaxf(x, -15.0f), 15.0f);
  float e = __expf(2.0f * x);
  return (e - 1.0f) / (e + 1.0f);
}
__device__ __forceinline__ us16 f2b(float f) {
  unsigned int u = __builtin_bit_cast(unsigned int, f);
  u = (u + 0x7fffu + ((u >> 16) & 1u)) >> 16;
  return (us16)u;
}
__device__ __forceinline__ float b2f(us16 h) {
  unsigned int u = ((unsigned int)h) << 16;
  return __builtin_bit_cast(float, u);
}
__device__ __forceinline__ unsigned pk2(float a, float b) {
  return (unsigned)f2b(a) | ((unsigned)f2b(b) << 16);
}
__device__ __forceinline__ void unp8(int4 v, float* t) {
  unsigned a = (unsigned)v.x, b = (unsigned)v.y, c = (unsigned)v.z, d = (unsigned)v.w;
  t[0] = b2f((us16)(a & 0xffff)); t[1] = b2f((us16)(a >> 16));
  t[2] = b2f((us16)(b & 0xffff)); t[3] = b2f((us16)(b >> 16));
  t[4] = b2f((us16)(c & 0xffff)); t[5] = b2f((us16)(c >> 16));
  t[6] = b2f((us16)(d & 0xffff)); t[7] = b2f((us16)(d >> 16));
}

// async global->LDS, 16B per lane; ldst is the wave-uniform base, HW adds lane*16
__device__ __forceinline__ void stage16(const us16* gsrc, us16* ldst) {
  __builtin_amdgcn_global_load_lds(
      (const __attribute__((address_space(1))) unsigned int*)(const void*)gsrc,
      (__attribute__((address_space(3))) unsigned int*)(void*)ldst, 16, 0, 0);
}
// 128B-row tiles (Kstep=64): slot = chunk ^ (row&7)  -> 2-way (free)
__device__ __forceinline__ bf16x8 frag_rd(const us16* base, int row, int byte_in_row) {
  int byte = row * 128 + (byte_in_row ^ ((row & 7) << 4));
  return *(const bf16x8*)((const char*)base + byte);
}
// 64B-row tiles (Kstep=32): slot = chunk ^ ((row>>1)&3) -> 2-way (free)
__device__ __forceinline__ bf16x8 frd32(const us16* tilebase, int row, int ck16) {
  int slot = ck16 ^ ((row >> 1) & 3);
  return *(const bf16x8*)(tilebase + row * 32 + slot * 8);
}

// ---------------- degree / norm / CSR build ----------------
__global__ void k_deg(const int* __restrict__ dst, int* __restrict__ indeg, int E) {
  int e = blockIdx.x * 256 + threadIdx.x;
  if (e < E) atomicAdd(&indeg[dst[e]], 1);
}

__global__ void k_dis(const int* __restrict__ indeg, float* __restrict__ dis, int n) {
  int i = blockIdx.x * 256 + threadIdx.x;
  if (i < n) dis[i] = rsqrtf((float)(indeg[i] + 1));  // +1 self-loop
}

// 3-phase parallel exclusive scan of indeg -> rp
__global__ __launch_bounds__(1024) void k_scan1(const int* __restrict__ v, int* __restrict__ rp,
                                                int* __restrict__ part, int n) {
  __shared__ int wsum[16];
  int base = blockIdx.x << 10;
  int t = threadIdx.x, lane = t & 63, wv = t >> 6;
  int val = (base + t < n) ? v[base + t] : 0;
  int s = val;
  #pragma unroll
  for (int off = 1; off < 64; off <<= 1) {
    int u = __shfl_up(s, off);
    if (lane >= off) s += u;
  }
  if (lane == 63) wsum[wv] = s;
  __syncthreads();
  int wadd = 0;
  #pragma unroll
  for (int w = 0; w < 16; ++w) wadd += (w < wv) ? wsum[w] : 0;
  if (base + t < n) rp[base + t] = wadd + s - val;
  if (t == 0) {
    int tot = 0;
    #pragma unroll
    for (int w = 0; w < 16; ++w) tot += wsum[w];
    part[blockIdx.x] = tot;
  }
}

__global__ __launch_bounds__(1024) void k_scan2(int* __restrict__ p, int nc) {
  __shared__ int wsum[16];
  int t = threadIdx.x, lane = t & 63, wv = t >> 6;
  int val = (t < nc) ? p[t] : 0;
  int s = val;
  #pragma unroll
  for (int off = 1; off < 64; off <<= 1) {
    int u = __shfl_up(s, off);
    if (lane >= off) s += u;
  }
  if (lane == 63) wsum[wv] = s;
  __syncthreads();
  int wadd = 0;
  #pragma unroll
  for (int w = 0; w < 16; ++w) wadd += (w < wv) ? wsum[w] : 0;
  if (t < nc) p[t] = wadd + s - val;
}

__global__ void k_scan3(int* __restrict__ rp, const int* __restrict__ part, int n, int total) {
  int i = blockIdx.x * 256 + threadIdx.x;
  if (i < n) rp[i] += part[i >> 10];
  else if (i == n) rp[n] = total;
}

__global__ void k_fill(const int* __restrict__ src, const int* __restrict__ dst,
                       const float* __restrict__ dis, int* __restrict__ cursor,
                       int* __restrict__ csrc, float* __restrict__ cw, int E) {
  int e = blockIdx.x * 256 + threadIdx.x;
  if (e >= E) return;
  int s = src[e], d = dst[e];
  int pos = atomicAdd(&cursor[d], 1);
  csrc[pos] = s;
  cw[pos] = dis[s] * dis[d];
}

// ---------------- repack: fp32 -> bf16 cast / transpose ----------------
__global__ void k_cast(const float* __restrict__ in, us16* __restrict__ out, int n) {
  int i = (blockIdx.x * 256 + threadIdx.x) * 4;
  if (i >= n) return;
  float4 v = *(const float4*)(in + i);
  *(ushort4*)(out + i) = make_ushort4(f2b(v.x), f2b(v.y), f2b(v.z), f2b(v.w));
}

// in [R,C] fp32 -> out [C,R] bf16
__global__ void k_tpose(const float* __restrict__ in, us16* __restrict__ out, int R, int C) {
  int t = blockIdx.x * 256 + threadIdx.x;
  if (t >= R * C) return;
  int r = t % R, c = t / R;
  out[(size_t)c * R + r] = f2b(in[(size_t)r * C + c]);
}

// ---------------- bf16 MFMA GEMM: C = act(A[M,K] @ Bt[Nc,K]^T + bias) ----------------
// block 128x128, 4 waves (2x2), wave tile 64x64, K-step 64.
// Double-buffered global_load_lds: stage(t+1) issued BEFORE compute(t); ONE barrier/step.
template<int ACT, int BIAS>
__global__ __launch_bounds__(256) void k_mm(const us16* __restrict__ A,
                                            const us16* __restrict__ Bt,
                                            const float* __restrict__ bias,
                                            us16* __restrict__ Cb,
                                            int M, int K, int Nc, int ny) {
  __shared__ __align__(16) us16 lds[2][2 * 8192];  // [buf][As|Bs], 32KB each
  const int bm = (blockIdx.x / ny) * 128;
  const int bn = (blockIdx.x % ny) * 128;
  const int tid = threadIdx.x;
  const int lane = tid & 63;
  const int wave = tid >> 6;
  const int wm = (wave >> 1) * 64;
  const int wn = (wave & 1) * 64;
  const int lr = lane & 15;
  const int lk = lane >> 4;
  const int srow = lane >> 3;                 // 0..7
  const int schk = (lane & 7) ^ srow;         // swizzled source chunk (16B)
  f32x4 acc[4][4] = {};

  auto stage = [&](int k0, us16* buf) {
    #pragma unroll
    for (int it = 0; it < 4; ++it) {
      int r8 = (wave * 4 + it) * 8;
      int ar = bm + r8 + srow; if (ar >= M) ar = M - 1;
      stage16(A + (size_t)ar * K + k0 + schk * 8, buf + r8 * 64);
      stage16(Bt + (size_t)(bn + r8 + srow) * K + k0 + schk * 8, buf + 8192 + r8 * 64);
    }
  };

  const int nk = K >> 6;
  stage(0, lds[0]);
  for (int t = 0; t < nk; ++t) {
    us16* cur = lds[t & 1];
    __syncthreads();                       // drains stage(t); buf (t+1)&1 free
    if (t + 1 < nk) stage((t + 1) << 6, lds[(t + 1) & 1]);
    #pragma unroll
    for (int kk = 0; kk < 2; ++kk) {
      bf16x8 af[4], bq[4];
      #pragma unroll
      for (int i = 0; i < 4; ++i) af[i] = frag_rd(cur, wm + i * 16 + lr, kk * 64 + lk * 16);
      #pragma unroll
      for (int j = 0; j < 4; ++j) bq[j] = frag_rd(cur + 8192, wn + j * 16 + lr, kk * 64 + lk * 16);
      #pragma unroll
      for (int i = 0; i < 4; ++i)
        #pragma unroll
        for (int j = 0; j < 4; ++j)
          acc[i][j] = __builtin_amdgcn_mfma_f32_16x16x32_bf16(af[i], bq[j], acc[i][j], 0, 0, 0);
    }
  }
  float bb[4];
  #pragma unroll
  for (int j = 0; j < 4; ++j) bb[j] = BIAS ? bias[bn + wn + j * 16 + lr] : 0.0f;
  #pragma unroll
  for (int i = 0; i < 4; ++i) {
    #pragma unroll
    for (int q = 0; q < 4; ++q) {
      int row = bm + wm + i * 16 + lk * 4 + q;
      if (row < M) {
        #pragma unroll
        for (int j = 0; j < 4; ++j) {
          int col = bn + wn + j * 16 + lr;
          float v = acc[i][j][q] + bb[j];
          if (ACT) v = lrelu(v);
          Cb[(size_t)row * Nc + col] = f2b(v);
        }
      }
    }
  }
}

// ---------------- CSR aggregation, F=128, edge loop unrolled x4 ----------------
template<int ACT>
__global__ __launch_bounds__(256) void k_agg128(const us16* __restrict__ hw, const int* __restrict__ rp,
                                                const int* __restrict__ csrc, const float* __restrict__ cw,
                                                const float* __restrict__ dis, const float* __restrict__ bias,
                                                us16* __restrict__ outp, int M) {
  int node = blockIdx.x * 16 + (threadIdx.x >> 4);
  int l = threadIdx.x & 15;
  if (node >= M) return;
  const us16* base = hw + l * 8;
  float acc[8], t0[8], t1[8], t2[8], t3[8];
  float dn = dis[node];
  float sw = dn * dn;
  {
    int4 v = *(const int4*)(base + (size_t)node * 128);
    unp8(v, t0);
    #pragma unroll
    for (int j = 0; j < 8; ++j) acc[j] = t0[j] * sw;
  }
  int e = rp[node], e1 = rp[node + 1];
  for (; e + 4 <= e1; e += 4) {
    int s0 = csrc[e], s1 = csrc[e + 1], s2 = csrc[e + 2], s3 = csrc[e + 3];
    float w0 = cw[e], w1 = cw[e + 1], w2 = cw[e + 2], w3 = cw[e + 3];
    int4 v0 = *(const int4*)(base + (size_t)s0 * 128);
    int4 v1 = *(const int4*)(base + (size_t)s1 * 128);
    int4 v2 = *(const int4*)(base + (size_t)s2 * 128);
    int4 v3 = *(const int4*)(base + (size_t)s3 * 128);
    unp8(v0, t0); unp8(v1, t1); unp8(v2, t2); unp8(v3, t3);
    #pragma unroll
    for (int j = 0; j < 8; ++j) acc[j] = fmaf(w0, t0[j], acc[j]);
    #pragma unroll
    for (int j = 0; j < 8; ++j) acc[j] = fmaf(w1, t1[j], acc[j]);
    #pragma unroll
    for (int j = 0; j < 8; ++j) acc[j] = fmaf(w2, t2[j], acc[j]);
    #pragma unroll
    for (int j = 0; j < 8; ++j) acc[j] = fmaf(w3, t3[j], acc[j]);
  }
  for (; e < e1; ++e) {
    int s0 = csrc[e];
    float w0 = cw[e];
    int4 v0 = *(const int4*)(base + (size_t)s0 * 128);
    unp8(v0, t0);
    #pragma unroll
    for (int j = 0; j < 8; ++j) acc[j] = fmaf(w0, t0[j], acc[j]);
  }
  if (ACT) {
    float4 b0 = *(const float4*)(bias + l * 8);
    float4 b1 = *(const float4*)(bias + l * 8 + 4);
    float bb[8] = {b0.x, b0.y, b0.z, b0.w, b1.x, b1.y, b1.z, b1.w};
    #pragma unroll
    for (int j = 0; j < 8; ++j) acc[j] = lrelu(acc[j] + bb[j]);
  }
  int4 o;
  o.x = (int)pk2(acc[0], acc[1]);
  o.y = (int)pk2(acc[2], acc[3]);
  o.z = (int)pk2(acc[4], acc[5]);
  o.w = (int)pk2(acc[6], acc[7]);
  *(int4*)(outp + (size_t)node * 128 + l * 8) = o;
}

// ---------------- fused GRU cell, single-pass 6-gate (MFMA) ----------------
// Block 64 rows x 64 H-cols, 4 waves (2x2), wave tile 32x32, K-step 32.
// Per step 8 tiles [64x32]: x, h, Wih r/z/n, Whh r/z/n. Double-buffered LDS,
// stage(t+1) issued before compute(t), one __syncthreads per step.
template<int H, int WB>
__global__ __launch_bounds__(256) void k_fgru(const us16* __restrict__ xb, const us16* __restrict__ hb,
                                              const us16* __restrict__ Wih, const us16* __restrict__ Whh,
                                              const float* __restrict__ bih, const float* __restrict__ bhh,
                                              float* __restrict__ emb, us16* __restrict__ embb,
                                              int M, int ny) {
  __shared__ __align__(16) us16 lds[2][8 * 2048];  // [buf][8 tiles of 64x32], 32KB each
  const int bn = (blockIdx.x % ny) * 64;
  const int bm = (blockIdx.x / ny) * 64;
  const int tid = threadIdx.x;
  const int lane = tid & 63, wave = tid >> 6;
  const int wm = (wave >> 1) * 32, wn = (wave & 1) * 32;
  const int lr = lane & 15, lk = lane >> 4;
  // staging geometry: one instr covers 16 rows x 4 chunks(16B); lane -> row r0+(l>>2), slot l&3
  const int sl_row = lane >> 2;                       // 0..15 row offset
  const int sl_chk = (lane & 3) ^ ((lane >> 3) & 3);  // inverse-swizzled source chunk

  f32x4 acc[6][2][2];
  #pragma unroll
  for (int g = 0; g < 6; ++g)
    #pragma unroll
    for (int i = 0; i < 2; ++i)
      #pragma unroll
      for (int j = 0; j < 2; ++j) acc[g][i][j] = {0.f, 0.f, 0.f, 0.f};

  auto stage_step = [&](int k0, us16* buf) {
    #pragma unroll
    for (int it = 0; it < 8; ++it) {
      int m = wave * 8 + it;
      int t = m >> 2, q = m & 3;
      int r0 = q * 16;
      int lrow = r0 + sl_row;
      const us16* src;
      if (t == 0) {
        int ar = bm + lrow; if (ar >= M) ar = M - 1;
        src = xb + (size_t)ar * H + k0 + sl_chk * 8;
      } else if (t == 1) {
        int ar = bm + lrow; if (ar >= M) ar = M - 1;
        src = hb + (size_t)ar * H + k0 + sl_chk * 8;
      } else {
        int w = t - 2;
        const us16* W = (w < 3) ? Wih : Whh;
        int g = (w < 3) ? w : w - 3;
        src = W + (size_t)(g * H + bn + lrow) * H + k0 + sl_chk * 8;
      }
      stage16(src, buf + t * 2048 + r0 * 32);
    }
  };

  const int nk = H >> 5;
  stage_step(0, lds[0]);
  for (int t = 0; t < nk; ++t) {
    us16* cur = lds[t & 1];
    __syncthreads();                       // stage(t) complete; other buffer free
    if (t + 1 < nk) stage_step((t + 1) << 5, lds[(t + 1) & 1]);
    bf16x8 ax[2], ah[2];
    #pragma unroll
    for (int i = 0; i < 2; ++i) {
      ax[i] = frd32(cur, wm + i * 16 + lr, lk);
      ah[i] = frd32(cur + 2048, wm + i * 16 + lr, lk);
    }
    #pragma unroll
    for (int g = 0; g < 3; ++g) {
      bf16x8 bqi[2], bqh[2];
      #pragma unroll
      for (int j = 0; j < 2; ++j) {
        bqi[j] = frd32(cur + (2 + g) * 2048, wn + j * 16 + lr, lk);
        bqh[j] = frd32(cur + (5 + g) * 2048, wn + j * 16 + lr, lk);
      }
      #pragma unroll
      for (int i = 0; i < 2; ++i)
        #pragma unroll
        for (int j = 0; j < 2; ++j) {
          acc[g][i][j] = __builtin_amdgcn_mfma_f32_16x16x32_bf16(ax[i], bqi[j], acc[g][i][j], 0, 0, 0);
          acc[3 + g][i][j] = __builtin_amdgcn_mfma_f32_16x16x32_bf16(ah[i], bqh[j], acc[3 + g][i][j], 0, 0, 0);
        }
    }
  }
  // ---- epilogue: gates ----
  #pragma unroll
  for (int j = 0; j < 2; ++j) {
    int col = bn + wn + j * 16 + lr;
    float bir = bih[col], biz = bih[H + col], bin = bih[2 * H + col];
    float bhr = bhh[col], bhz = bhh[H + col], bhn = bhh[2 * H + col];
    #pragma unroll
    for (int i = 0; i < 2; ++i) {
      #pragma unroll
      for (int q = 0; q < 4; ++q) {
        int row = bm + wm + i * 16 + lk * 4 + q;
        if (row >= M) continue;
        float r = fsigmoid(acc[0][i][j][q] + bir + acc[3][i][j][q] + bhr);
        float z = fsigmoid(acc[1][i][j][q] + biz + acc[4][i][j][q] + bhz);
        float n = ftanh(acc[2][i][j][q] + bin + r * (acc[5][i][j][q] + bhn));
        float hv = b2f(hb[(size_t)row * H + col]);
        float o = (1.0f - z) * n + z * hv;
        emb[(size_t)row * H + col] = o;
        if (WB) embb[(size_t)row * H + col] = f2b(o);
      }
    }
  }
}

// ---------------- post head: out[n] = sum_cols(emb1 @ Wpost + bpost) ----------------
__global__ __launch_bounds__(256) void k_post(const float* __restrict__ emb, const float* __restrict__ Wpost,
                                              const float* __restrict__ bpost, float* __restrict__ outv, int M) {
  int gw = (int)((blockIdx.x * 256 + threadIdx.x) >> 6);
  int lane = threadIdx.x & 63;
  if (gw >= M) return;
  float2 ev = *(const float2*)(emb + (size_t)gw * 128 + lane * 2);
  float4 wv = *(const float4*)(Wpost + lane * 4);
  float p = ev.x * (wv.x + wv.y) + ev.y * (wv.z + wv.w);
  #pragma unroll
  for (int o = 32; o > 0; o >>= 1) p += __shfl_xor(p, o);
  if (lane == 0) outv[gw] = p + bpost[0] + bpost[1];
}

extern "C" void kernel_launch(void* const* d_in, const int* in_sizes, int n_in,
                              void* d_out, int out_size, void* d_ws, size_t ws_size,
                              hipStream_t stream) {
  const float* x     = (const float*)d_in[0];
  const int*   ei    = (const int*)d_in[1];
  const float* prev0 = (const float*)d_in[2];
  const float* prev1 = (const float*)d_in[3];
  const float* Wp1   = (const float*)d_in[4];
  const float* bp1   = (const float*)d_in[5];
  const float* Wp2   = (const float*)d_in[6];
  const float* bp2   = (const float*)d_in[7];
  const float* Wc1   = (const float*)d_in[8];
  const float* bc1   = (const float*)d_in[9];
  const float* Wc2   = (const float*)d_in[10];
  const float* bc2   = (const float*)d_in[11];
  const float* Wih1  = (const float*)d_in[12];
  const float* Whh1  = (const float*)d_in[13];
  const float* bih1  = (const float*)d_in[14];
  const float* bhh1  = (const float*)d_in[15];
  const float* Wih2  = (const float*)d_in[16];
  const float* Whh2  = (const float*)d_in[17];
  const float* bih2  = (const float*)d_in[18];
  const float* bhh2  = (const float*)d_in[19];
  const float* Wpost = (const float*)d_in[20];
  const float* bpost = (const float*)d_in[21];

  const int N = in_sizes[0] / 128;   // 100000
  const int E = in_sizes[1] / 2;     // 1600000
  const int* srcp = ei;
  const int* dstp = ei + E;

  char* wsb = (char*)d_ws;
  size_t off = 0;
  auto alloc = [&](size_t bytes) -> void* {
    void* p = wsb + off;
    off = (off + bytes + 255) & ~(size_t)255;
    return p;
  };
  float* dis    = (float*)alloc((size_t)N * 4);
  int*   indeg  = (int*)alloc((size_t)N * 4);
  int*   rp     = (int*)alloc((size_t)(N + 1) * 4);
  int*   part   = (int*)alloc((size_t)1024 * 4);
  int*   cursor = (int*)alloc((size_t)N * 4);
  int*   csrc   = (int*)alloc((size_t)E * 4);
  float* cw     = (float*)alloc((size_t)E * 4);
  us16* xb    = (us16*)alloc((size_t)N * 128 * 2);
  us16* p0b   = (us16*)alloc((size_t)N * 256 * 2);
  us16* p1b   = (us16*)alloc((size_t)N * 128 * 2);
  us16* WtP1  = (us16*)alloc((size_t)256 * 128 * 2);
  us16* WtP2  = (us16*)alloc((size_t)128 * 256 * 2);
  us16* WtC1  = (us16*)alloc((size_t)256 * 128 * 2);
  us16* WtC2  = (us16*)alloc((size_t)128 * 256 * 2);
  us16* Wih1b = (us16*)alloc((size_t)768 * 256 * 2);
  us16* Whh1b = (us16*)alloc((size_t)768 * 256 * 2);
  us16* Wih2b = (us16*)alloc((size_t)384 * 128 * 2);
  us16* Whh2b = (us16*)alloc((size_t)384 * 128 * 2);
  us16* bufA  = (us16*)alloc((size_t)N * 256 * 2);  // MLP hidden / GCN1 out
  us16* bufB  = (us16*)alloc((size_t)N * 128 * 2);  // MLP out / GCN2 lin out
  us16* bufD  = (us16*)alloc((size_t)N * 128 * 2);  // agg out
  us16* emb0b = (us16*)alloc((size_t)N * 256 * 2);
  (void)ws_size; (void)n_in; (void)out_size;

  float* outv = (float*)d_out;
  float* emb0 = outv + N;
  float* emb1 = emb0 + (size_t)N * 256;

  auto cg = [](long n) { return (unsigned)((n / 4 + 255) / 256); };

  // weight/activation repack
  k_cast<<<cg((long)N * 128), 256, 0, stream>>>(x, xb, N * 128);
  k_cast<<<cg((long)N * 256), 256, 0, stream>>>(prev0, p0b, N * 256);
  k_cast<<<cg((long)N * 128), 256, 0, stream>>>(prev1, p1b, N * 128);
  k_cast<<<cg(768 * 256), 256, 0, stream>>>(Wih1, Wih1b, 768 * 256);
  k_cast<<<cg(768 * 256), 256, 0, stream>>>(Whh1, Whh1b, 768 * 256);
  k_cast<<<cg(384 * 128), 256, 0, stream>>>(Wih2, Wih2b, 384 * 128);
  k_cast<<<cg(384 * 128), 256, 0, stream>>>(Whh2, Whh2b, 384 * 128);
  k_tpose<<<(128 * 256 + 255) / 256, 256, 0, stream>>>(Wp1, WtP1, 128, 256);
  k_tpose<<<(256 * 128 + 255) / 256, 256, 0, stream>>>(Wp2, WtP2, 256, 128);
  k_tpose<<<(128 * 256 + 255) / 256, 256, 0, stream>>>(Wc1, WtC1, 128, 256);
  k_tpose<<<(256 * 128 + 255) / 256, 256, 0, stream>>>(Wc2, WtC2, 256, 128);

  // CSR build (parallel scan)
  hipMemsetAsync(indeg, 0, (size_t)N * 4, stream);
  k_deg<<<(E + 255) / 256, 256, 0, stream>>>(dstp, indeg, E);
  k_dis<<<(N + 255) / 256, 256, 0, stream>>>(indeg, dis, N);
  const int NC = (N + 1023) / 1024;  // 98
  k_scan1<<<NC, 1024, 0, stream>>>(indeg, rp, part, N);
  k_scan2<<<1, 1024, 0, stream>>>(part, NC);
  k_scan3<<<(N + 256) / 256, 256, 0, stream>>>(rp, part, N, E);
  hipMemcpyAsync(cursor, rp, (size_t)N * 4, hipMemcpyDeviceToDevice, stream);
  k_fill<<<(E + 255) / 256, 256, 0, stream>>>(srcp, dstp, dis, cursor, csrc, cw, E);

  const int MB = (N + 127) / 128;   // 782 (k_mm)
  const int FB = (N + 63) / 64;     // 1563 (k_fgru)
  const int AB = (N + 15) / 16;     // 6250 (k_agg128)

  // preprocess MLP
  k_mm<1, 1><<<MB * 2, 256, 0, stream>>>(xb, WtP1, bp1, bufA, N, 128, 256, 2);
  k_mm<1, 1><<<MB, 256, 0, stream>>>(bufA, WtP2, bp2, bufB, N, 256, 128, 1);
  // GCN1: aggregate FIRST (linearity), then linear+bias+leaky
  k_agg128<0><<<AB, 256, 0, stream>>>(bufB, rp, csrc, cw, dis, nullptr, bufD, N);
  k_mm<1, 1><<<MB * 2, 256, 0, stream>>>(bufD, WtC1, bc1, bufA, N, 128, 256, 2);
  // GRU1 fused (single-pass, dbuf), bn-inner for L2 reuse
  k_fgru<256, 1><<<FB * 4, 256, 0, stream>>>(bufA, p0b, Wih1b, Whh1b, bih1, bhh1,
                                             emb0, emb0b, N, 4);
  // GCN2: linear first (256->128), then aggregate with bias+leaky
  k_mm<0, 0><<<MB, 256, 0, stream>>>(emb0b, WtC2, nullptr, bufB, N, 256, 128, 1);
  k_agg128<1><<<AB, 256, 0, stream>>>(bufB, rp, csrc, cw, dis, bc2, bufD, N);
  // GRU2 fused
  k_fgru<128, 0><<<FB * 2, 256, 0, stream>>>(bufD, p1b, Wih2b, Whh2b, bih2, bhh2,
                                             emb1, nullptr, N, 2);
  // post head
  k_post<<<(N + 3) / 4, 256, 0, stream>>>(emb1, Wpost, bpost, outv, N);
}